// Round 5
// baseline (811.741 us; speedup 1.0000x reference)
//
#include <hip/hip_runtime.h>

#define NN 100000
#define NE 800000
// D = 160, 2D = 320, F = 128

typedef _Float16 half8 __attribute__((ext_vector_type(8)));
typedef _Float16 half4 __attribute__((ext_vector_type(4)));
typedef float floatx4 __attribute__((ext_vector_type(4)));

#define LDB(Wf, f) (*(const half8*)&(Wf)[(f) * 512])

// ---------------------------------------------------------------- zero
__global__ __launch_bounds__(256) void k_zero(float4* __restrict__ p, int n4) {
  int i = blockIdx.x * 256 + threadIdx.x;
  if (i < n4) p[i] = make_float4(0.f, 0.f, 0.f, 0.f);
}

// ---------------------------------------------------------------- fragment-pack all weights
// Fragment f=(kk,i): 1KB chunk, lane reads 16B at dst[f*1024 + lane*16].
// b for lane(mrow,quad) of frag (kk,i) = W[i*16+mrow][kk*32+quad*8 .. +8].
// Segments: We 32 frags | Wo 40 | Wu 2x100 | Wp 2x2x50.  472 frags x 64 lanes.
__global__ __launch_bounds__(256) void k_pack(
    const float* __restrict__ w_enc, const float* __restrict__ w_out,
    const float* __restrict__ wu, const float* __restrict__ wm,
    _Float16* __restrict__ WeP, _Float16* __restrict__ WoP,
    _Float16* __restrict__ WuP, _Float16* __restrict__ WpP) {
  int gid = blockIdx.x * 256 + threadIdx.x;  // grid exact: 118*256 = 30208 = 472*64
  int fid = gid >> 6, lane = gid & 63;
  int mrow = lane & 15, quad = lane >> 4;
  const float* src; _Float16* dst; int stride, NI, f, g;
  if (fid < 32) {
    f = fid; g = f; src = w_enc; dst = WeP; stride = 128; NI = 8;
  } else if (fid < 72) {
    f = fid - 32; g = f; src = w_out; dst = WoP; stride = 160; NI = 8;
  } else if (fid < 272) {
    f = fid - 72; g = f % 100; src = wu + (f / 100) * 51200; dst = WuP; stride = 320; NI = 10;
  } else {
    f = fid - 272; g = f % 50;
    int l = f / 100, h = (f % 100) / 50;
    src = wm + l * 51200 + h * 160; dst = WpP; stride = 320; NI = 10;
  }
  int kk = g / NI, i = g - kk * NI;
  const float* sp = src + (size_t)(i * 16 + mrow) * stride + kk * 32 + quad * 8;
  float4 f0 = *(const float4*)sp;
  float4 f1 = *(const float4*)(sp + 4);
  half8 v = {(_Float16)f0.x, (_Float16)f0.y, (_Float16)f0.z, (_Float16)f0.w,
             (_Float16)f1.x, (_Float16)f1.y, (_Float16)f1.z, (_Float16)f1.w};
  *(half8*)&dst[(size_t)(f * 64 + lane) * 8] = v;
}

// ---------------------------------------------------------------- CSR build
__global__ __launch_bounds__(256) void k_count_i(const int* __restrict__ ei,
                                                 int* __restrict__ cnti) {
  int e = blockIdx.x * 256 + threadIdx.x;  // grid exact: 3125*256 = 800000
  atomicAdd(&cnti[ei[NE + e]], 1);
}

__global__ __launch_bounds__(256) void k_scan1(const int* __restrict__ cnti,
                                               int* __restrict__ off,
                                               int* __restrict__ bsum) {
  __shared__ int sh[256];
  const int t = threadIdx.x;
  const int i = blockIdx.x * 256 + t;  // grid 391 covers 100096
  int v = (i < NN) ? cnti[i] : 0;
  sh[t] = v;
  __syncthreads();
  for (int d = 1; d < 256; d <<= 1) {
    int add = (t >= d) ? sh[t - d] : 0;
    __syncthreads();
    sh[t] += add;
    __syncthreads();
  }
  if (i < NN) off[i] = sh[t] - v;
  if (t == 255) bsum[blockIdx.x] = sh[255];
}

__global__ __launch_bounds__(512) void k_scan2(const int* __restrict__ bsum,
                                               int* __restrict__ bsum2) {
  __shared__ int sh[512];
  const int t = threadIdx.x;
  int v = (t < 391) ? bsum[t] : 0;
  sh[t] = v;
  __syncthreads();
  for (int d = 1; d < 512; d <<= 1) {
    int add = (t >= d) ? sh[t - d] : 0;
    __syncthreads();
    sh[t] += add;
    __syncthreads();
  }
  if (t < 391) bsum2[t] = sh[t] - v;
}

__global__ __launch_bounds__(256) void k_scan3(int* __restrict__ off,
                                               const int* __restrict__ bsum2,
                                               int* __restrict__ cursor) {
  const int i = blockIdx.x * 256 + threadIdx.x;
  if (i < NN) {
    int o = off[i] + bsum2[blockIdx.x];
    off[i] = o;
    cursor[i] = o;
  }
  if (i == 0) off[NN] = NE;
}

__global__ __launch_bounds__(256) void k_scatter(const int* __restrict__ ei,
                                                 const float* __restrict__ ew,
                                                 int* __restrict__ cursor,
                                                 int2* __restrict__ selist) {
  int e = blockIdx.x * 256 + threadIdx.x;  // grid exact 3125
  int dst = ei[NE + e];
  int pos = atomicAdd(&cursor[dst], 1);
  selist[pos] = make_int2(ei[e], __float_as_int(ew[e]));
}

// ---------------------------------------------------------------- helpers
__device__ __forceinline__ half8 cvt8(const float* p) {
  float4 f0 = *(const float4*)p;
  float4 f1 = *(const float4*)(p + 4);
  half8 a = {(_Float16)f0.x, (_Float16)f0.y, (_Float16)f0.z, (_Float16)f0.w,
             (_Float16)f1.x, (_Float16)f1.y, (_Float16)f1.z, (_Float16)f1.w};
  return a;
}

// wave-local vectorized h16 writer: this wave's 16 rows x 20 pieces = 320 chunks
__device__ __forceinline__ void write_h16_wave(_Float16* __restrict__ h16,
                                               const _Float16* tile, int n0,
                                               int w, int lane) {
#pragma unroll
  for (int u = 0; u < 5; ++u) {
    int c = lane + u * 64;  // 320 = 16 * 20
    int row = c / 20, col = (c - row * 20) * 8;
    int node = n0 + w * 16 + row;
    if (node < NN)
      *(half8*)&h16[(size_t)node * 160 + col] = *(const half8*)&tile[(w * 16 + row) * 168 + col];
  }
}

// ---------------------------------------------------------------- shared phase 2: P = tile @ Wp^T
// Wave-local: this wave's 16 rows only; B direct from fragment-packed WpP.
__device__ __forceinline__ void phase2_proj(
    const _Float16* __restrict__ WpP, const float* __restrict__ bm,
    _Float16* __restrict__ P, const _Float16* tile,
    int lane, int w, int mrow, int quad, int n0) {
#pragma unroll 1
  for (int half_ = 0; half_ < 2; ++half_) {
    const _Float16* Wf = WpP + half_ * 25600 + lane * 8;
    floatx4 acc2[10];
#pragma unroll
    for (int i = 0; i < 10; ++i) acc2[i] = (floatx4)0.f;
#pragma unroll
    for (int kk = 0; kk < 5; ++kk) {
      half8 a = *(const half8*)&tile[(w * 16 + mrow) * 168 + kk * 32 + quad * 8];
#pragma unroll
      for (int i = 0; i < 10; ++i) {
        half8 b = LDB(Wf, kk * 10 + i);
        acc2[i] = __builtin_amdgcn_mfma_f32_16x16x32_f16(a, b, acc2[i], 0, 0, 0);
      }
    }
#pragma unroll
    for (int r = 0; r < 4; ++r) {
      const int row = quad * 4 + r;
      const int node = n0 + w * 16 + row;
      if (node < NN) {
        _Float16* prow = &P[(size_t)node * 320 + half_ * 160];
#pragma unroll
        for (int i = 0; i < 10; ++i) {
          int jj = i * 16 + mrow;
          prow[jj] = (_Float16)(acc2[i][r] + (half_ ? bm[jj] : 0.f));
        }
      }
    }
  }
}

// ---------------------------------------------------------------- fused encoder + proj (128 thr, 32 nodes)
__global__ __launch_bounds__(128, 8) void k_encode_proj(
    const float* __restrict__ x, const float* __restrict__ tsp,
    const _Float16* __restrict__ WeP,
    const float* __restrict__ b_enc, const float* __restrict__ g_enc,
    const float* __restrict__ be_enc,
    const float* __restrict__ w_time, const float* __restrict__ b_time,
    const float* __restrict__ g_time, const float* __restrict__ be_time,
    const _Float16* __restrict__ WpP, const float* __restrict__ bm,
    _Float16* __restrict__ h16, _Float16* __restrict__ P) {
  __shared__ _Float16 tile[32 * 168];
  const int t = threadIdx.x;
  const int lane = t & 63, w = t >> 6;
  const int mrow = lane & 15, quad = lane >> 4;
  const int n0 = blockIdx.x * 32;  // grid 3125
  int arow = n0 + w * 16 + mrow; if (arow > NN - 1) arow = NN - 1;
  const float* xrow = x + (size_t)arow * 128;
  // A fragments (f32 -> f16)
  half8 areg[4];
#pragma unroll
  for (int kt = 0; kt < 4; ++kt) areg[kt] = cvt8(&xrow[kt * 32 + quad * 8]);
  // time-LN closed-form constants
  float mw = 0.f, mb = 0.f;
  for (int d = 0; d < 32; ++d) { mw += w_time[d]; mb += b_time[d]; }
  mw *= (1.f / 32.f); mb *= (1.f / 32.f);
  float A = 0.f, B = 0.f, C = 0.f;
  for (int d = 0; d < 32; ++d) {
    float a = w_time[d] - mw, c = b_time[d] - mb;
    A = fmaf(a, a, A); B = fmaf(a, c, B); C = fmaf(c, c, C);
  }
  A *= (1.f / 32.f); B *= (1.f / 32.f); C *= (1.f / 32.f);
  // phase 1: h = x @ We^T (B direct from packed global)
  floatx4 acc[8];
#pragma unroll
  for (int i = 0; i < 8; ++i) acc[i] = (floatx4)0.f;
  const _Float16* Wf = WeP + lane * 8;
#pragma unroll
  for (int kk = 0; kk < 4; ++kk) {
    half8 a = areg[kk];
#pragma unroll
    for (int i = 0; i < 8; ++i) {
      half8 b = LDB(Wf, kk * 8 + i);
      acc[i] = __builtin_amdgcn_mfma_f32_16x16x32_f16(a, b, acc[i], 0, 0, 0);
    }
  }
  // epilogue: LN(128) + relu -> tile
#pragma unroll
  for (int r = 0; r < 4; ++r) {
    const int row = quad * 4 + r;
    float v[8], s = 0.f, ss = 0.f;
#pragma unroll
    for (int i = 0; i < 8; ++i) {
      v[i] = acc[i][r] + b_enc[i * 16 + mrow];
      s += v[i]; ss = fmaf(v[i], v[i], ss);
    }
#pragma unroll
    for (int off = 1; off < 16; off <<= 1) { s += __shfl_xor(s, off); ss += __shfl_xor(ss, off); }
    const float m = s * (1.f / 128.f);
    const float rs = rsqrtf(ss * (1.f / 128.f) - m * m + 1e-5f);
#pragma unroll
    for (int i = 0; i < 8; ++i) {
      int j = i * 16 + mrow;
      tile[(w * 16 + row) * 168 + j] =
          (_Float16)fmaxf(fmaf((v[i] - m) * rs, g_enc[j], be_enc[j]), 0.f);
    }
  }
  // time dims 128..159 (closed-form LN), wave-local: 16 nodes x 32 dims = 512
#pragma unroll
  for (int rr = 0; rr < 8; ++rr) {
    int q = lane + rr * 64;
    int nn = q >> 5, d = q & 31;
    int node = n0 + w * 16 + nn;
    int nodec = (node > NN - 1) ? NN - 1 : node;
    float tsv = tsp[nodec];
    float mt = fmaf(mw, tsv, mb);
    float rst = rsqrtf(fmaf(fmaf(A, tsv, 2.f * B), tsv, C) + 1e-5f);
    float vv = fmaf(w_time[d], tsv, b_time[d]);
    float y = fmaxf(fmaf((vv - mt) * rst, g_time[d], be_time[d]), 0.f);
    tile[(w * 16 + nn) * 168 + 128 + d] = (_Float16)y;
  }
  // wave-local tile handoff: within-wave LDS ordering only (no barrier)
  write_h16_wave(h16, tile, n0, w, lane);
  phase2_proj(WpP, bm, P, tile, lane, w, mrow, quad, n0);
}

// ---------------------------------------------------------------- edge aggregate (CSR, 2-way unroll)
__global__ __launch_bounds__(256) void k_edge3(
    const _Float16* __restrict__ P, const int* __restrict__ off,
    const int2* __restrict__ selist,
    const float* __restrict__ gm, const float* __restrict__ bem,
    _Float16* __restrict__ msum16) {
  const int t = threadIdx.x;
  const int jg = t & 31, g = t >> 5;
  const int n = blockIdx.x * 8 + g;  // grid exact: 12500*8 = 100000
  float gmv[5], bev[5], pdv[5];
#pragma unroll
  for (int i = 0; i < 4; ++i) { gmv[i] = gm[4 * jg + i]; bev[i] = bem[4 * jg + i]; }
  gmv[4] = gm[128 + jg]; bev[4] = bem[128 + jg];
  const _Float16* pd = P + (size_t)n * 320 + 160;
  half4 pdh = *(const half4*)&pd[4 * jg];
  pdv[0] = (float)pdh.x; pdv[1] = (float)pdh.y; pdv[2] = (float)pdh.z; pdv[3] = (float)pdh.w;
  pdv[4] = (float)pd[128 + jg];
  float acc[5] = {0.f, 0.f, 0.f, 0.f, 0.f};
  const int e0 = off[n], e1 = off[n + 1];
  int k = e0;
  for (; k + 1 < e1; k += 2) {
    int2 seA = selist[k], seB = selist[k + 1];
    const _Float16* psA = P + (size_t)seA.x * 320;
    const _Float16* psB = P + (size_t)seB.x * 320;
    const float weA = __int_as_float(seA.y), weB = __int_as_float(seB.y);
    half4 a4 = *(const half4*)&psA[4 * jg];
    half4 b4 = *(const half4*)&psB[4 * jg];
    float a5 = (float)psA[128 + jg], b5 = (float)psB[128 + jg];
    float vA[5], vB[5];
    vA[0] = (float)a4.x + pdv[0]; vA[1] = (float)a4.y + pdv[1];
    vA[2] = (float)a4.z + pdv[2]; vA[3] = (float)a4.w + pdv[3]; vA[4] = a5 + pdv[4];
    vB[0] = (float)b4.x + pdv[0]; vB[1] = (float)b4.y + pdv[1];
    vB[2] = (float)b4.z + pdv[2]; vB[3] = (float)b4.w + pdv[3]; vB[4] = b5 + pdv[4];
    float sA = 0.f, ssA = 0.f, sB = 0.f, ssB = 0.f;
#pragma unroll
    for (int i = 0; i < 5; ++i) {
      sA += vA[i]; ssA = fmaf(vA[i], vA[i], ssA);
      sB += vB[i]; ssB = fmaf(vB[i], vB[i], ssB);
    }
#pragma unroll
    for (int o = 1; o < 32; o <<= 1) {
      sA += __shfl_xor(sA, o); ssA += __shfl_xor(ssA, o);
      sB += __shfl_xor(sB, o); ssB += __shfl_xor(ssB, o);
    }
    const float mA = sA * (1.f / 160.f), mB = sB * (1.f / 160.f);
    const float rsA = rsqrtf(ssA * (1.f / 160.f) - mA * mA + 1e-5f);
    const float rsB = rsqrtf(ssB * (1.f / 160.f) - mB * mB + 1e-5f);
#pragma unroll
    for (int i = 0; i < 5; ++i) {
      acc[i] = fmaf(fmaxf(fmaf((vA[i] - mA) * rsA, gmv[i], bev[i]), 0.f), weA, acc[i]);
      acc[i] = fmaf(fmaxf(fmaf((vB[i] - mB) * rsB, gmv[i], bev[i]), 0.f), weB, acc[i]);
    }
  }
  if (k < e1) {
    int2 se = selist[k];
    const _Float16* ps = P + (size_t)se.x * 320;
    const float we = __int_as_float(se.y);
    half4 s4 = *(const half4*)&ps[4 * jg];
    float v[5], s = 0.f, ss = 0.f;
    v[0] = (float)s4.x + pdv[0]; v[1] = (float)s4.y + pdv[1];
    v[2] = (float)s4.z + pdv[2]; v[3] = (float)s4.w + pdv[3];
    v[4] = (float)ps[128 + jg] + pdv[4];
#pragma unroll
    for (int i = 0; i < 5; ++i) { s += v[i]; ss = fmaf(v[i], v[i], ss); }
#pragma unroll
    for (int o = 1; o < 32; o <<= 1) { s += __shfl_xor(s, o); ss += __shfl_xor(ss, o); }
    const float m = s * (1.f / 160.f);
    const float rs = rsqrtf(ss * (1.f / 160.f) - m * m + 1e-5f);
#pragma unroll
    for (int i = 0; i < 5; ++i)
      acc[i] = fmaf(fmaxf(fmaf((v[i] - m) * rs, gmv[i], bev[i]), 0.f), we, acc[i]);
  }
  const float c = (float)(e1 - e0);
  const float ic = (c > 0.f) ? 1.f / (c + 1e-8f) : 0.f;
  _Float16* orow = msum16 + (size_t)n * 160;
  half4 o4 = {(_Float16)(acc[0] * ic), (_Float16)(acc[1] * ic),
              (_Float16)(acc[2] * ic), (_Float16)(acc[3] * ic)};
  *(half4*)&orow[4 * jg] = o4;
  orow[128 + jg] = (_Float16)(acc[4] * ic);
}

// ---------------------------------------------------------------- shared update phase 1 -> tile (wave-local)
__device__ __forceinline__ void update_phase1(
    const _Float16* __restrict__ h16, const _Float16* __restrict__ msum16,
    const _Float16* __restrict__ WuP, const float* __restrict__ bu,
    const float* __restrict__ gu, const float* __restrict__ beu,
    const float* __restrict__ wg, const float* __restrict__ bg,
    _Float16* tile, int lane, int w, int mrow, int quad, int n0) {
  int arow = n0 + w * 16 + mrow; if (arow > NN - 1) arow = NN - 1;
  const _Float16* hrowp = h16 + (size_t)arow * 160;
  const _Float16* mrowp = msum16 + (size_t)arow * 160;
  // A fragments
  half8 areg[10];
#pragma unroll
  for (int kt = 0; kt < 5; ++kt) areg[kt] = *(const half8*)&hrowp[kt * 32 + quad * 8];
#pragma unroll
  for (int kt = 5; kt < 10; ++kt) areg[kt] = *(const half8*)&mrowp[kt * 32 + quad * 8 - 160];
  // gate dot from hoisted h-fragments
  float gp = 0.f;
#pragma unroll
  for (int kt = 0; kt < 5; ++kt) {
    const int k0 = kt * 32 + quad * 8;
    float4 g0 = *(const float4*)&wg[k0];
    float4 g1 = *(const float4*)&wg[k0 + 4];
    gp = fmaf((float)areg[kt][0], g0.x, gp); gp = fmaf((float)areg[kt][1], g0.y, gp);
    gp = fmaf((float)areg[kt][2], g0.z, gp); gp = fmaf((float)areg[kt][3], g0.w, gp);
    gp = fmaf((float)areg[kt][4], g1.x, gp); gp = fmaf((float)areg[kt][5], g1.y, gp);
    gp = fmaf((float)areg[kt][6], g1.z, gp); gp = fmaf((float)areg[kt][7], g1.w, gp);
  }
  gp += __shfl_xor(gp, 16); gp += __shfl_xor(gp, 32);
  const float twv = 1.f / (1.f + expf(-(gp + bg[0])));
  // K=320, B direct from packed global — zero barriers
  floatx4 acc[10];
#pragma unroll
  for (int i = 0; i < 10; ++i) acc[i] = (floatx4)0.f;
  const _Float16* Wf = WuP + lane * 8;
#pragma unroll
  for (int kk = 0; kk < 10; ++kk) {
    half8 a = areg[kk];
#pragma unroll
    for (int i = 0; i < 10; ++i) {
      half8 b = LDB(Wf, kk * 10 + i);
      acc[i] = __builtin_amdgcn_mfma_f32_16x16x32_f16(a, b, acc[i], 0, 0, 0);
    }
  }
  // epilogue: LN + relu + gate blend -> tile
#pragma unroll
  for (int r = 0; r < 4; ++r) {
    const int row = quad * 4 + r;
    const int node = n0 + w * 16 + row;
    const int nodec = (node > NN - 1) ? NN - 1 : node;
    float v[10], s = 0.f, ss = 0.f;
#pragma unroll
    for (int i = 0; i < 10; ++i) {
      v[i] = acc[i][r] + bu[i * 16 + mrow];
      s += v[i]; ss = fmaf(v[i], v[i], ss);
    }
#pragma unroll
    for (int off = 1; off < 16; off <<= 1) { s += __shfl_xor(s, off); ss += __shfl_xor(ss, off); }
    const float m = s * (1.f / 160.f);
    const float rs = rsqrtf(ss * (1.f / 160.f) - m * m + 1e-5f);
    const float g = __shfl(twv, row);
    const _Float16* hr = h16 + (size_t)nodec * 160;
#pragma unroll
    for (int i = 0; i < 10; ++i) {
      int j = i * 16 + mrow;
      float hnew = fmaxf(fmaf((v[i] - m) * rs, gu[j], beu[j]), 0.f);
      float hold = (float)hr[j];
      tile[(w * 16 + row) * 168 + j] = (_Float16)fmaf(g, hnew - hold, hold);
    }
  }
}

// ---------------------------------------------------------------- fused update + proj (128 thr, 32 nodes)
__global__ __launch_bounds__(128, 8) void k_update_proj(
    _Float16* __restrict__ h16, const _Float16* __restrict__ msum16,
    const _Float16* __restrict__ WuP, const float* __restrict__ bu,
    const float* __restrict__ gu, const float* __restrict__ beu,
    const float* __restrict__ wg, const float* __restrict__ bg,
    const _Float16* __restrict__ WpP, const float* __restrict__ bm,
    _Float16* __restrict__ P) {
  __shared__ _Float16 tile[32 * 168];
  const int t = threadIdx.x;
  const int lane = t & 63, w = t >> 6;
  const int mrow = lane & 15, quad = lane >> 4;
  const int n0 = blockIdx.x * 32;  // grid 3125
  update_phase1(h16, msum16, WuP, bu, gu, beu, wg, bg, tile, lane, w, mrow, quad, n0);
  // wave-local handoff: no barrier
  write_h16_wave(h16, tile, n0, w, lane);
  phase2_proj(WpP, bm, P, tile, lane, w, mrow, quad, n0);
}

// ---------------------------------------------------------------- fused update + output proj + L2 norm
__global__ __launch_bounds__(128, 8) void k_update_out(
    const _Float16* __restrict__ h16, const _Float16* __restrict__ msum16,
    const _Float16* __restrict__ WuP, const float* __restrict__ bu,
    const float* __restrict__ gu, const float* __restrict__ beu,
    const float* __restrict__ wg, const float* __restrict__ bg,
    const _Float16* __restrict__ WoP, const float* __restrict__ b_out,
    float* __restrict__ out) {
  __shared__ _Float16 tile[32 * 168];
  const int t = threadIdx.x;
  const int lane = t & 63, w = t >> 6;
  const int mrow = lane & 15, quad = lane >> 4;
  const int n0 = blockIdx.x * 32;  // grid 3125
  update_phase1(h16, msum16, WuP, bu, gu, beu, wg, bg, tile, lane, w, mrow, quad, n0);
  // phase 2: out = L2norm(tile @ Wo^T + b_out); wave-local rows, no barrier
  floatx4 acc2[8];
#pragma unroll
  for (int i = 0; i < 8; ++i) acc2[i] = (floatx4)0.f;
  const _Float16* Wf2 = WoP + lane * 8;
#pragma unroll
  for (int kk = 0; kk < 5; ++kk) {
    half8 a = *(const half8*)&tile[(w * 16 + mrow) * 168 + kk * 32 + quad * 8];
#pragma unroll
    for (int i = 0; i < 8; ++i) {
      half8 b = LDB(Wf2, kk * 8 + i);
      acc2[i] = __builtin_amdgcn_mfma_f32_16x16x32_f16(a, b, acc2[i], 0, 0, 0);
    }
  }
#pragma unroll
  for (int r = 0; r < 4; ++r) {
    const int row = quad * 4 + r;
    const int node = n0 + w * 16 + row;
    float v[8], ss = 0.f;
#pragma unroll
    for (int i = 0; i < 8; ++i) {
      v[i] = acc2[i][r] + b_out[i * 16 + mrow];
      ss = fmaf(v[i], v[i], ss);
    }
#pragma unroll
    for (int off = 1; off < 16; off <<= 1) ss += __shfl_xor(ss, off);
    const float inv = 1.f / fmaxf(sqrtf(ss), 1e-12f);
    if (node < NN) {
#pragma unroll
      for (int i = 0; i < 8; ++i)
        out[(size_t)node * 128 + i * 16 + mrow] = v[i] * inv;
    }
  }
}

// ---------------------------------------------------------------- launch
extern "C" void kernel_launch(void* const* d_in, const int* in_sizes, int n_in,
                              void* d_out, int out_size, void* d_ws, size_t ws_size,
                              hipStream_t stream) {
  (void)in_sizes; (void)n_in; (void)out_size; (void)ws_size;
  const float* x       = (const float*)d_in[0];
  const int*   ei      = (const int*)  d_in[1];
  const float* ew      = (const float*)d_in[2];
  const float* tsp     = (const float*)d_in[3];
  const float* w_enc   = (const float*)d_in[4];
  const float* b_enc   = (const float*)d_in[5];
  const float* g_enc   = (const float*)d_in[6];
  const float* be_enc  = (const float*)d_in[7];
  const float* w_time  = (const float*)d_in[8];
  const float* b_time  = (const float*)d_in[9];
  const float* g_time  = (const float*)d_in[10];
  const float* be_time = (const float*)d_in[11];
  const float* wm      = (const float*)d_in[12];
  const float* bm      = (const float*)d_in[13];
  const float* gm      = (const float*)d_in[14];
  const float* bem     = (const float*)d_in[15];
  const float* wu      = (const float*)d_in[16];
  const float* bu      = (const float*)d_in[17];
  const float* gu      = (const float*)d_in[18];
  const float* beu     = (const float*)d_in[19];
  const float* wg      = (const float*)d_in[20];
  const float* bg      = (const float*)d_in[21];
  const float* w_out   = (const float*)d_in[22];
  const float* b_out   = (const float*)d_in[23];
  float* out = (float*)d_out;

  // ws layout (bytes): h16 f16[NN*160] @0 (32M) | msum16 f16[NN*160] @32,000,000 (32M)
  //   P f16[NN*320] @64,000,000 (64M) | WuP @128,000,000 (204,800) | WoP @128,204,800 (40,960)
  char* ws = (char*)d_ws;
  _Float16* h16    = (_Float16*)ws;
  _Float16* msum16 = (_Float16*)(ws + 32000000);
  _Float16* P      = (_Float16*)(ws + 64000000);
  _Float16* WuP16  = (_Float16*)(ws + 128000000);
  _Float16* WoP16  = (_Float16*)(ws + 128204800);
  // d_out doubles as scratch; k_update_out reads only ws-resident scratch.
  char* ob = (char*)d_out;
  _Float16* WpP16 = (_Float16*)ob;            // 204,800
  _Float16* WeP16 = (_Float16*)(ob + 204800); // 32,768
  int* off    = (int*)(ob + 237568);          // 400,016
  int* cnti   = (int*)(ob + 637584);          // 400,000
  int* cursor = (int*)(ob + 1037584);         // 400,000
  int* bsum   = (int*)(ob + 1437584);         // 1,568
  int* bsum2  = (int*)(ob + 1439152);         // 1,568
  int2* selist = (int2*)(ob + 1440720);       // 6,400,000 -> 7,840,720 < 51,200,000

  // weight prep + CSR build (edges static across layers: build once)
  k_zero<<<dim3(98), dim3(256), 0, stream>>>((float4*)cnti, 25000);
  k_pack<<<dim3(118), dim3(256), 0, stream>>>(w_enc, w_out, wu, wm,
                                              WeP16, WoP16, WuP16, WpP16);
  k_count_i<<<dim3(3125), dim3(256), 0, stream>>>(ei, cnti);
  k_scan1<<<dim3(391), dim3(256), 0, stream>>>(cnti, off, bsum);
  k_scan2<<<dim3(1), dim3(512), 0, stream>>>(bsum, bsum2);
  k_scan3<<<dim3(391), dim3(256), 0, stream>>>(off, bsum2, cursor);
  k_scatter<<<dim3(3125), dim3(256), 0, stream>>>(ei, ew, cursor, selist);

  k_encode_proj<<<dim3(3125), dim3(128), 0, stream>>>(
      x, tsp, WeP16, b_enc, g_enc, be_enc, w_time, b_time, g_time, be_time,
      WpP16, bm, h16, P);
  k_edge3<<<dim3(12500), dim3(256), 0, stream>>>(P, off, selist, gm, bem, msum16);
  k_update_proj<<<dim3(3125), dim3(128), 0, stream>>>(
      h16, msum16, WuP16, bu, gu, beu, wg, bg,
      WpP16 + 51200, bm + 160, P);
  k_edge3<<<dim3(12500), dim3(256), 0, stream>>>(P, off, selist, gm + 160, bem + 160, msum16);
  k_update_out<<<dim3(3125), dim3(128), 0, stream>>>(
      h16, msum16, WuP16 + 51200, bu + 160, gu + 160, beu + 160, wg + 160, bg + 1,
      WoP16, b_out, out);
}

// Round 6
// 554.965 us; speedup vs baseline: 1.4627x; 1.4627x over previous
//
#include <hip/hip_runtime.h>

#define NN 100000
#define NE 800000
// D = 160, 2D = 320, F = 128

typedef _Float16 half8 __attribute__((ext_vector_type(8)));
typedef _Float16 half4 __attribute__((ext_vector_type(4)));
typedef float floatx4 __attribute__((ext_vector_type(4)));

#define LDB(Wf, f) (*(const half8*)&(Wf)[(f) * 512])

// ---------------------------------------------------------------- zero
__global__ __launch_bounds__(256) void k_zero(float4* __restrict__ p, int n4) {
  int i = blockIdx.x * 256 + threadIdx.x;
  if (i < n4) p[i] = make_float4(0.f, 0.f, 0.f, 0.f);
}

// ---------------------------------------------------------------- fragment-pack all weights
// Fragment f=(kk,i): 1KB chunk, lane reads 16B at dst[f*1024 + lane*16].
// b for lane(mrow,quad) of frag (kk,i) = W[i*16+mrow][kk*32+quad*8 .. +8].
// Segments: We 32 frags | Wo 40 | Wu 2x100 | Wp 2x2x50.  472 frags x 64 lanes.
__global__ __launch_bounds__(256) void k_pack(
    const float* __restrict__ w_enc, const float* __restrict__ w_out,
    const float* __restrict__ wu, const float* __restrict__ wm,
    _Float16* __restrict__ WeP, _Float16* __restrict__ WoP,
    _Float16* __restrict__ WuP, _Float16* __restrict__ WpP) {
  int gid = blockIdx.x * 256 + threadIdx.x;  // grid exact: 118*256 = 30208 = 472*64
  int fid = gid >> 6, lane = gid & 63;
  int mrow = lane & 15, quad = lane >> 4;
  const float* src; _Float16* dst; int stride, NI, f, g;
  if (fid < 32) {
    f = fid; g = f; src = w_enc; dst = WeP; stride = 128; NI = 8;
  } else if (fid < 72) {
    f = fid - 32; g = f; src = w_out; dst = WoP; stride = 160; NI = 8;
  } else if (fid < 272) {
    f = fid - 72; g = f % 100; src = wu + (f / 100) * 51200; dst = WuP; stride = 320; NI = 10;
  } else {
    f = fid - 272; g = f % 50;
    int l = f / 100, h = (f % 100) / 50;
    src = wm + l * 51200 + h * 160; dst = WpP; stride = 320; NI = 10;
  }
  int kk = g / NI, i = g - kk * NI;
  const float* sp = src + (size_t)(i * 16 + mrow) * stride + kk * 32 + quad * 8;
  float4 f0 = *(const float4*)sp;
  float4 f1 = *(const float4*)(sp + 4);
  half8 v = {(_Float16)f0.x, (_Float16)f0.y, (_Float16)f0.z, (_Float16)f0.w,
             (_Float16)f1.x, (_Float16)f1.y, (_Float16)f1.z, (_Float16)f1.w};
  *(half8*)&dst[(size_t)(f * 64 + lane) * 8] = v;
}

// ---------------------------------------------------------------- CSR build
__global__ __launch_bounds__(256) void k_count_i(const int* __restrict__ ei,
                                                 int* __restrict__ cnti) {
  int e = blockIdx.x * 256 + threadIdx.x;  // grid exact: 3125*256 = 800000
  atomicAdd(&cnti[ei[NE + e]], 1);
}

__global__ __launch_bounds__(256) void k_scan1(const int* __restrict__ cnti,
                                               int* __restrict__ off,
                                               int* __restrict__ bsum) {
  __shared__ int sh[256];
  const int t = threadIdx.x;
  const int i = blockIdx.x * 256 + t;  // grid 391 covers 100096
  int v = (i < NN) ? cnti[i] : 0;
  sh[t] = v;
  __syncthreads();
  for (int d = 1; d < 256; d <<= 1) {
    int add = (t >= d) ? sh[t - d] : 0;
    __syncthreads();
    sh[t] += add;
    __syncthreads();
  }
  if (i < NN) off[i] = sh[t] - v;
  if (t == 255) bsum[blockIdx.x] = sh[255];
}

__global__ __launch_bounds__(512) void k_scan2(const int* __restrict__ bsum,
                                               int* __restrict__ bsum2) {
  __shared__ int sh[512];
  const int t = threadIdx.x;
  int v = (t < 391) ? bsum[t] : 0;
  sh[t] = v;
  __syncthreads();
  for (int d = 1; d < 512; d <<= 1) {
    int add = (t >= d) ? sh[t - d] : 0;
    __syncthreads();
    sh[t] += add;
    __syncthreads();
  }
  if (t < 391) bsum2[t] = sh[t] - v;
}

__global__ __launch_bounds__(256) void k_scan3(int* __restrict__ off,
                                               const int* __restrict__ bsum2,
                                               int* __restrict__ cursor) {
  const int i = blockIdx.x * 256 + threadIdx.x;
  if (i < NN) {
    int o = off[i] + bsum2[blockIdx.x];
    off[i] = o;
    cursor[i] = o;
  }
  if (i == 0) off[NN] = NE;
}

__global__ __launch_bounds__(256) void k_scatter(const int* __restrict__ ei,
                                                 const float* __restrict__ ew,
                                                 int* __restrict__ cursor,
                                                 int2* __restrict__ selist) {
  int e = blockIdx.x * 256 + threadIdx.x;  // grid exact 3125
  int dst = ei[NE + e];
  int pos = atomicAdd(&cursor[dst], 1);
  selist[pos] = make_int2(ei[e], __float_as_int(ew[e]));
}

// ---------------------------------------------------------------- helpers
__device__ __forceinline__ half8 cvt8(const float* p) {
  float4 f0 = *(const float4*)p;
  float4 f1 = *(const float4*)(p + 4);
  half8 a = {(_Float16)f0.x, (_Float16)f0.y, (_Float16)f0.z, (_Float16)f0.w,
             (_Float16)f1.x, (_Float16)f1.y, (_Float16)f1.z, (_Float16)f1.w};
  return a;
}

// wave-local vectorized h16 writer: this wave's 16 rows x 20 pieces = 320 chunks
__device__ __forceinline__ void write_h16_wave(_Float16* __restrict__ h16,
                                               const _Float16* tile, int n0,
                                               int w, int lane) {
#pragma unroll
  for (int u = 0; u < 5; ++u) {
    int c = lane + u * 64;  // 320 = 16 * 20
    int row = c / 20, col = (c - row * 20) * 8;
    int node = n0 + w * 16 + row;
    if (node < NN)
      *(half8*)&h16[(size_t)node * 160 + col] = *(const half8*)&tile[(w * 16 + row) * 168 + col];
  }
}

// ---------------------------------------------------------------- shared phase 2: P = tile @ Wp^T
// Wave-local: this wave's 16 rows only; B direct from fragment-packed WpP.
__device__ __forceinline__ void phase2_proj(
    const _Float16* __restrict__ WpP, const float* __restrict__ bm,
    _Float16* __restrict__ P, const _Float16* tile,
    int lane, int w, int mrow, int quad, int n0) {
#pragma unroll 1
  for (int half_ = 0; half_ < 2; ++half_) {
    const _Float16* Wf = WpP + half_ * 25600 + lane * 8;
    floatx4 acc2[10];
#pragma unroll
    for (int i = 0; i < 10; ++i) acc2[i] = (floatx4)0.f;
#pragma unroll
    for (int kk = 0; kk < 5; ++kk) {
      half8 a = *(const half8*)&tile[(w * 16 + mrow) * 168 + kk * 32 + quad * 8];
#pragma unroll
      for (int i = 0; i < 10; ++i) {
        half8 b = LDB(Wf, kk * 10 + i);
        acc2[i] = __builtin_amdgcn_mfma_f32_16x16x32_f16(a, b, acc2[i], 0, 0, 0);
      }
    }
#pragma unroll
    for (int r = 0; r < 4; ++r) {
      const int row = quad * 4 + r;
      const int node = n0 + w * 16 + row;
      if (node < NN) {
        _Float16* prow = &P[(size_t)node * 320 + half_ * 160];
#pragma unroll
        for (int i = 0; i < 10; ++i) {
          int jj = i * 16 + mrow;
          prow[jj] = (_Float16)(acc2[i][r] + (half_ ? bm[jj] : 0.f));
        }
      }
    }
  }
}

// ---------------------------------------------------------------- fused encoder + proj (128 thr, 32 nodes)
__global__ __launch_bounds__(128, 4) void k_encode_proj(
    const float* __restrict__ x, const float* __restrict__ tsp,
    const _Float16* __restrict__ WeP,
    const float* __restrict__ b_enc, const float* __restrict__ g_enc,
    const float* __restrict__ be_enc,
    const float* __restrict__ w_time, const float* __restrict__ b_time,
    const float* __restrict__ g_time, const float* __restrict__ be_time,
    const _Float16* __restrict__ WpP, const float* __restrict__ bm,
    _Float16* __restrict__ h16, _Float16* __restrict__ P) {
  __shared__ _Float16 tile[32 * 168];
  const int t = threadIdx.x;
  const int lane = t & 63, w = t >> 6;
  const int mrow = lane & 15, quad = lane >> 4;
  const int n0 = blockIdx.x * 32;  // grid 3125
  int arow = n0 + w * 16 + mrow; if (arow > NN - 1) arow = NN - 1;
  const float* xrow = x + (size_t)arow * 128;
  // A fragments (f32 -> f16)
  half8 areg[4];
#pragma unroll
  for (int kt = 0; kt < 4; ++kt) areg[kt] = cvt8(&xrow[kt * 32 + quad * 8]);
  // time-LN closed-form constants
  float mw = 0.f, mb = 0.f;
  for (int d = 0; d < 32; ++d) { mw += w_time[d]; mb += b_time[d]; }
  mw *= (1.f / 32.f); mb *= (1.f / 32.f);
  float A = 0.f, B = 0.f, C = 0.f;
  for (int d = 0; d < 32; ++d) {
    float a = w_time[d] - mw, c = b_time[d] - mb;
    A = fmaf(a, a, A); B = fmaf(a, c, B); C = fmaf(c, c, C);
  }
  A *= (1.f / 32.f); B *= (1.f / 32.f); C *= (1.f / 32.f);
  // phase 1: h = x @ We^T (B direct from packed global)
  floatx4 acc[8];
#pragma unroll
  for (int i = 0; i < 8; ++i) acc[i] = (floatx4)0.f;
  const _Float16* Wf = WeP + lane * 8;
#pragma unroll
  for (int kk = 0; kk < 4; ++kk) {
    half8 a = areg[kk];
#pragma unroll
    for (int i = 0; i < 8; ++i) {
      half8 b = LDB(Wf, kk * 8 + i);
      acc[i] = __builtin_amdgcn_mfma_f32_16x16x32_f16(a, b, acc[i], 0, 0, 0);
    }
  }
  // epilogue: LN(128) + relu -> tile
#pragma unroll
  for (int r = 0; r < 4; ++r) {
    const int row = quad * 4 + r;
    float v[8], s = 0.f, ss = 0.f;
#pragma unroll
    for (int i = 0; i < 8; ++i) {
      v[i] = acc[i][r] + b_enc[i * 16 + mrow];
      s += v[i]; ss = fmaf(v[i], v[i], ss);
    }
#pragma unroll
    for (int off = 1; off < 16; off <<= 1) { s += __shfl_xor(s, off); ss += __shfl_xor(ss, off); }
    const float m = s * (1.f / 128.f);
    const float rs = rsqrtf(ss * (1.f / 128.f) - m * m + 1e-5f);
#pragma unroll
    for (int i = 0; i < 8; ++i) {
      int j = i * 16 + mrow;
      tile[(w * 16 + row) * 168 + j] =
          (_Float16)fmaxf(fmaf((v[i] - m) * rs, g_enc[j], be_enc[j]), 0.f);
    }
  }
  // time dims 128..159 (closed-form LN), wave-local: 16 nodes x 32 dims = 512
#pragma unroll
  for (int rr = 0; rr < 8; ++rr) {
    int q = lane + rr * 64;
    int nn = q >> 5, d = q & 31;
    int node = n0 + w * 16 + nn;
    int nodec = (node > NN - 1) ? NN - 1 : node;
    float tsv = tsp[nodec];
    float mt = fmaf(mw, tsv, mb);
    float rst = rsqrtf(fmaf(fmaf(A, tsv, 2.f * B), tsv, C) + 1e-5f);
    float vv = fmaf(w_time[d], tsv, b_time[d]);
    float y = fmaxf(fmaf((vv - mt) * rst, g_time[d], be_time[d]), 0.f);
    tile[(w * 16 + nn) * 168 + 128 + d] = (_Float16)y;
  }
  // wave-local tile handoff: within-wave LDS ordering only (no barrier)
  write_h16_wave(h16, tile, n0, w, lane);
  phase2_proj(WpP, bm, P, tile, lane, w, mrow, quad, n0);
}

// ---------------------------------------------------------------- edge aggregate (CSR, 2-way unroll)
__global__ __launch_bounds__(256) void k_edge3(
    const _Float16* __restrict__ P, const int* __restrict__ off,
    const int2* __restrict__ selist,
    const float* __restrict__ gm, const float* __restrict__ bem,
    _Float16* __restrict__ msum16) {
  const int t = threadIdx.x;
  const int jg = t & 31, g = t >> 5;
  const int n = blockIdx.x * 8 + g;  // grid exact: 12500*8 = 100000
  float gmv[5], bev[5], pdv[5];
#pragma unroll
  for (int i = 0; i < 4; ++i) { gmv[i] = gm[4 * jg + i]; bev[i] = bem[4 * jg + i]; }
  gmv[4] = gm[128 + jg]; bev[4] = bem[128 + jg];
  const _Float16* pd = P + (size_t)n * 320 + 160;
  half4 pdh = *(const half4*)&pd[4 * jg];
  pdv[0] = (float)pdh.x; pdv[1] = (float)pdh.y; pdv[2] = (float)pdh.z; pdv[3] = (float)pdh.w;
  pdv[4] = (float)pd[128 + jg];
  float acc[5] = {0.f, 0.f, 0.f, 0.f, 0.f};
  const int e0 = off[n], e1 = off[n + 1];
  int k = e0;
  for (; k + 1 < e1; k += 2) {
    int2 seA = selist[k], seB = selist[k + 1];
    const _Float16* psA = P + (size_t)seA.x * 320;
    const _Float16* psB = P + (size_t)seB.x * 320;
    const float weA = __int_as_float(seA.y), weB = __int_as_float(seB.y);
    half4 a4 = *(const half4*)&psA[4 * jg];
    half4 b4 = *(const half4*)&psB[4 * jg];
    float a5 = (float)psA[128 + jg], b5 = (float)psB[128 + jg];
    float vA[5], vB[5];
    vA[0] = (float)a4.x + pdv[0]; vA[1] = (float)a4.y + pdv[1];
    vA[2] = (float)a4.z + pdv[2]; vA[3] = (float)a4.w + pdv[3]; vA[4] = a5 + pdv[4];
    vB[0] = (float)b4.x + pdv[0]; vB[1] = (float)b4.y + pdv[1];
    vB[2] = (float)b4.z + pdv[2]; vB[3] = (float)b4.w + pdv[3]; vB[4] = b5 + pdv[4];
    float sA = 0.f, ssA = 0.f, sB = 0.f, ssB = 0.f;
#pragma unroll
    for (int i = 0; i < 5; ++i) {
      sA += vA[i]; ssA = fmaf(vA[i], vA[i], ssA);
      sB += vB[i]; ssB = fmaf(vB[i], vB[i], ssB);
    }
#pragma unroll
    for (int o = 1; o < 32; o <<= 1) {
      sA += __shfl_xor(sA, o); ssA += __shfl_xor(ssA, o);
      sB += __shfl_xor(sB, o); ssB += __shfl_xor(ssB, o);
    }
    const float mA = sA * (1.f / 160.f), mB = sB * (1.f / 160.f);
    const float rsA = rsqrtf(ssA * (1.f / 160.f) - mA * mA + 1e-5f);
    const float rsB = rsqrtf(ssB * (1.f / 160.f) - mB * mB + 1e-5f);
#pragma unroll
    for (int i = 0; i < 5; ++i) {
      acc[i] = fmaf(fmaxf(fmaf((vA[i] - mA) * rsA, gmv[i], bev[i]), 0.f), weA, acc[i]);
      acc[i] = fmaf(fmaxf(fmaf((vB[i] - mB) * rsB, gmv[i], bev[i]), 0.f), weB, acc[i]);
    }
  }
  if (k < e1) {
    int2 se = selist[k];
    const _Float16* ps = P + (size_t)se.x * 320;
    const float we = __int_as_float(se.y);
    half4 s4 = *(const half4*)&ps[4 * jg];
    float v[5], s = 0.f, ss = 0.f;
    v[0] = (float)s4.x + pdv[0]; v[1] = (float)s4.y + pdv[1];
    v[2] = (float)s4.z + pdv[2]; v[3] = (float)s4.w + pdv[3];
    v[4] = (float)ps[128 + jg] + pdv[4];
#pragma unroll
    for (int i = 0; i < 5; ++i) { s += v[i]; ss = fmaf(v[i], v[i], ss); }
#pragma unroll
    for (int o = 1; o < 32; o <<= 1) { s += __shfl_xor(s, o); ss += __shfl_xor(ss, o); }
    const float m = s * (1.f / 160.f);
    const float rs = rsqrtf(ss * (1.f / 160.f) - m * m + 1e-5f);
#pragma unroll
    for (int i = 0; i < 5; ++i)
      acc[i] = fmaf(fmaxf(fmaf((v[i] - m) * rs, gmv[i], bev[i]), 0.f), we, acc[i]);
  }
  const float c = (float)(e1 - e0);
  const float ic = (c > 0.f) ? 1.f / (c + 1e-8f) : 0.f;
  _Float16* orow = msum16 + (size_t)n * 160;
  half4 o4 = {(_Float16)(acc[0] * ic), (_Float16)(acc[1] * ic),
              (_Float16)(acc[2] * ic), (_Float16)(acc[3] * ic)};
  *(half4*)&orow[4 * jg] = o4;
  orow[128 + jg] = (_Float16)(acc[4] * ic);
}

// ---------------------------------------------------------------- shared update phase 1 -> tile (wave-local)
__device__ __forceinline__ void update_phase1(
    const _Float16* __restrict__ h16, const _Float16* __restrict__ msum16,
    const _Float16* __restrict__ WuP, const float* __restrict__ bu,
    const float* __restrict__ gu, const float* __restrict__ beu,
    const float* __restrict__ wg, const float* __restrict__ bg,
    _Float16* tile, int lane, int w, int mrow, int quad, int n0) {
  int arow = n0 + w * 16 + mrow; if (arow > NN - 1) arow = NN - 1;
  const _Float16* hrowp = h16 + (size_t)arow * 160;
  const _Float16* mrowp = msum16 + (size_t)arow * 160;
  // A fragments
  half8 areg[10];
#pragma unroll
  for (int kt = 0; kt < 5; ++kt) areg[kt] = *(const half8*)&hrowp[kt * 32 + quad * 8];
#pragma unroll
  for (int kt = 5; kt < 10; ++kt) areg[kt] = *(const half8*)&mrowp[kt * 32 + quad * 8 - 160];
  // gate dot from hoisted h-fragments
  float gp = 0.f;
#pragma unroll
  for (int kt = 0; kt < 5; ++kt) {
    const int k0 = kt * 32 + quad * 8;
    float4 g0 = *(const float4*)&wg[k0];
    float4 g1 = *(const float4*)&wg[k0 + 4];
    gp = fmaf((float)areg[kt][0], g0.x, gp); gp = fmaf((float)areg[kt][1], g0.y, gp);
    gp = fmaf((float)areg[kt][2], g0.z, gp); gp = fmaf((float)areg[kt][3], g0.w, gp);
    gp = fmaf((float)areg[kt][4], g1.x, gp); gp = fmaf((float)areg[kt][5], g1.y, gp);
    gp = fmaf((float)areg[kt][6], g1.z, gp); gp = fmaf((float)areg[kt][7], g1.w, gp);
  }
  gp += __shfl_xor(gp, 16); gp += __shfl_xor(gp, 32);
  const float twv = 1.f / (1.f + expf(-(gp + bg[0])));
  // K=320, B direct from packed global — zero barriers
  floatx4 acc[10];
#pragma unroll
  for (int i = 0; i < 10; ++i) acc[i] = (floatx4)0.f;
  const _Float16* Wf = WuP + lane * 8;
#pragma unroll
  for (int kk = 0; kk < 10; ++kk) {
    half8 a = areg[kk];
#pragma unroll
    for (int i = 0; i < 10; ++i) {
      half8 b = LDB(Wf, kk * 10 + i);
      acc[i] = __builtin_amdgcn_mfma_f32_16x16x32_f16(a, b, acc[i], 0, 0, 0);
    }
  }
  // epilogue: LN + relu + gate blend -> tile
#pragma unroll
  for (int r = 0; r < 4; ++r) {
    const int row = quad * 4 + r;
    const int node = n0 + w * 16 + row;
    const int nodec = (node > NN - 1) ? NN - 1 : node;
    float v[10], s = 0.f, ss = 0.f;
#pragma unroll
    for (int i = 0; i < 10; ++i) {
      v[i] = acc[i][r] + bu[i * 16 + mrow];
      s += v[i]; ss = fmaf(v[i], v[i], ss);
    }
#pragma unroll
    for (int off = 1; off < 16; off <<= 1) { s += __shfl_xor(s, off); ss += __shfl_xor(ss, off); }
    const float m = s * (1.f / 160.f);
    const float rs = rsqrtf(ss * (1.f / 160.f) - m * m + 1e-5f);
    const float g = __shfl(twv, row);
    const _Float16* hr = h16 + (size_t)nodec * 160;
#pragma unroll
    for (int i = 0; i < 10; ++i) {
      int j = i * 16 + mrow;
      float hnew = fmaxf(fmaf((v[i] - m) * rs, gu[j], beu[j]), 0.f);
      float hold = (float)hr[j];
      tile[(w * 16 + row) * 168 + j] = (_Float16)fmaf(g, hnew - hold, hold);
    }
  }
}

// ---------------------------------------------------------------- fused update + proj (128 thr, 32 nodes)
__global__ __launch_bounds__(128, 4) void k_update_proj(
    _Float16* __restrict__ h16, const _Float16* __restrict__ msum16,
    const _Float16* __restrict__ WuP, const float* __restrict__ bu,
    const float* __restrict__ gu, const float* __restrict__ beu,
    const float* __restrict__ wg, const float* __restrict__ bg,
    const _Float16* __restrict__ WpP, const float* __restrict__ bm,
    _Float16* __restrict__ P) {
  __shared__ _Float16 tile[32 * 168];
  const int t = threadIdx.x;
  const int lane = t & 63, w = t >> 6;
  const int mrow = lane & 15, quad = lane >> 4;
  const int n0 = blockIdx.x * 32;  // grid 3125
  update_phase1(h16, msum16, WuP, bu, gu, beu, wg, bg, tile, lane, w, mrow, quad, n0);
  // wave-local handoff: no barrier
  write_h16_wave(h16, tile, n0, w, lane);
  phase2_proj(WpP, bm, P, tile, lane, w, mrow, quad, n0);
}

// ---------------------------------------------------------------- fused update + output proj + L2 norm
__global__ __launch_bounds__(128, 4) void k_update_out(
    const _Float16* __restrict__ h16, const _Float16* __restrict__ msum16,
    const _Float16* __restrict__ WuP, const float* __restrict__ bu,
    const float* __restrict__ gu, const float* __restrict__ beu,
    const float* __restrict__ wg, const float* __restrict__ bg,
    const _Float16* __restrict__ WoP, const float* __restrict__ b_out,
    float* __restrict__ out) {
  __shared__ _Float16 tile[32 * 168];
  const int t = threadIdx.x;
  const int lane = t & 63, w = t >> 6;
  const int mrow = lane & 15, quad = lane >> 4;
  const int n0 = blockIdx.x * 32;  // grid 3125
  update_phase1(h16, msum16, WuP, bu, gu, beu, wg, bg, tile, lane, w, mrow, quad, n0);
  // phase 2: out = L2norm(tile @ Wo^T + b_out); wave-local rows, no barrier
  floatx4 acc2[8];
#pragma unroll
  for (int i = 0; i < 8; ++i) acc2[i] = (floatx4)0.f;
  const _Float16* Wf2 = WoP + lane * 8;
#pragma unroll
  for (int kk = 0; kk < 5; ++kk) {
    half8 a = *(const half8*)&tile[(w * 16 + mrow) * 168 + kk * 32 + quad * 8];
#pragma unroll
    for (int i = 0; i < 8; ++i) {
      half8 b = LDB(Wf2, kk * 8 + i);
      acc2[i] = __builtin_amdgcn_mfma_f32_16x16x32_f16(a, b, acc2[i], 0, 0, 0);
    }
  }
#pragma unroll
  for (int r = 0; r < 4; ++r) {
    const int row = quad * 4 + r;
    const int node = n0 + w * 16 + row;
    float v[8], ss = 0.f;
#pragma unroll
    for (int i = 0; i < 8; ++i) {
      v[i] = acc2[i][r] + b_out[i * 16 + mrow];
      ss = fmaf(v[i], v[i], ss);
    }
#pragma unroll
    for (int off = 1; off < 16; off <<= 1) ss += __shfl_xor(ss, off);
    const float inv = 1.f / fmaxf(sqrtf(ss), 1e-12f);
    if (node < NN) {
#pragma unroll
      for (int i = 0; i < 8; ++i)
        out[(size_t)node * 128 + i * 16 + mrow] = v[i] * inv;
    }
  }
}

// ---------------------------------------------------------------- launch
extern "C" void kernel_launch(void* const* d_in, const int* in_sizes, int n_in,
                              void* d_out, int out_size, void* d_ws, size_t ws_size,
                              hipStream_t stream) {
  (void)in_sizes; (void)n_in; (void)out_size; (void)ws_size;
  const float* x       = (const float*)d_in[0];
  const int*   ei      = (const int*)  d_in[1];
  const float* ew      = (const float*)d_in[2];
  const float* tsp     = (const float*)d_in[3];
  const float* w_enc   = (const float*)d_in[4];
  const float* b_enc   = (const float*)d_in[5];
  const float* g_enc   = (const float*)d_in[6];
  const float* be_enc  = (const float*)d_in[7];
  const float* w_time  = (const float*)d_in[8];
  const float* b_time  = (const float*)d_in[9];
  const float* g_time  = (const float*)d_in[10];
  const float* be_time = (const float*)d_in[11];
  const float* wm      = (const float*)d_in[12];
  const float* bm      = (const float*)d_in[13];
  const float* gm      = (const float*)d_in[14];
  const float* bem     = (const float*)d_in[15];
  const float* wu      = (const float*)d_in[16];
  const float* bu      = (const float*)d_in[17];
  const float* gu      = (const float*)d_in[18];
  const float* beu     = (const float*)d_in[19];
  const float* wg      = (const float*)d_in[20];
  const float* bg      = (const float*)d_in[21];
  const float* w_out   = (const float*)d_in[22];
  const float* b_out   = (const float*)d_in[23];
  float* out = (float*)d_out;

  // ws layout (bytes): h16 f16[NN*160] @0 (32M) | msum16 f16[NN*160] @32,000,000 (32M)
  //   P f16[NN*320] @64,000,000 (64M) | WuP @128,000,000 (204,800) | WoP @128,204,800 (40,960)
  char* ws = (char*)d_ws;
  _Float16* h16    = (_Float16*)ws;
  _Float16* msum16 = (_Float16*)(ws + 32000000);
  _Float16* P      = (_Float16*)(ws + 64000000);
  _Float16* WuP16  = (_Float16*)(ws + 128000000);
  _Float16* WoP16  = (_Float16*)(ws + 128204800);
  // d_out doubles as scratch; k_update_out reads only ws-resident scratch.
  char* ob = (char*)d_out;
  _Float16* WpP16 = (_Float16*)ob;            // 204,800
  _Float16* WeP16 = (_Float16*)(ob + 204800); // 32,768
  int* off    = (int*)(ob + 237568);          // 400,016
  int* cnti   = (int*)(ob + 637584);          // 400,000
  int* cursor = (int*)(ob + 1037584);         // 400,000
  int* bsum   = (int*)(ob + 1437584);         // 1,568
  int* bsum2  = (int*)(ob + 1439152);         // 1,568
  int2* selist = (int2*)(ob + 1440720);       // 6,400,000 -> 7,840,720 < 51,200,000

  // weight prep + CSR build (edges static across layers: build once)
  k_zero<<<dim3(98), dim3(256), 0, stream>>>((float4*)cnti, 25000);
  k_pack<<<dim3(118), dim3(256), 0, stream>>>(w_enc, w_out, wu, wm,
                                              WeP16, WoP16, WuP16, WpP16);
  k_count_i<<<dim3(3125), dim3(256), 0, stream>>>(ei, cnti);
  k_scan1<<<dim3(391), dim3(256), 0, stream>>>(cnti, off, bsum);
  k_scan2<<<dim3(1), dim3(512), 0, stream>>>(bsum, bsum2);
  k_scan3<<<dim3(391), dim3(256), 0, stream>>>(off, bsum2, cursor);
  k_scatter<<<dim3(3125), dim3(256), 0, stream>>>(ei, ew, cursor, selist);

  k_encode_proj<<<dim3(3125), dim3(128), 0, stream>>>(
      x, tsp, WeP16, b_enc, g_enc, be_enc, w_time, b_time, g_time, be_time,
      WpP16, bm, h16, P);
  k_edge3<<<dim3(12500), dim3(256), 0, stream>>>(P, off, selist, gm, bem, msum16);
  k_update_proj<<<dim3(3125), dim3(128), 0, stream>>>(
      h16, msum16, WuP16, bu, gu, beu, wg, bg,
      WpP16 + 51200, bm + 160, P);
  k_edge3<<<dim3(12500), dim3(256), 0, stream>>>(P, off, selist, gm + 160, bem + 160, msum16);
  k_update_out<<<dim3(3125), dim3(128), 0, stream>>>(
      h16, msum16, WuP16 + 51200, bu + 160, gu + 160, beu + 160, wg + 160, bg + 1,
      WoP16, b_out, out);
}

// Round 7
// 554.253 us; speedup vs baseline: 1.4646x; 1.0013x over previous
//
#include <hip/hip_runtime.h>

#define NN 100000
#define NE 800000
// D = 160, 2D = 320, F = 128

typedef _Float16 half8 __attribute__((ext_vector_type(8)));
typedef _Float16 half4 __attribute__((ext_vector_type(4)));
typedef float floatx4 __attribute__((ext_vector_type(4)));

#define LDB(Wf, f) (*(const half8*)&(Wf)[(f) * 512])

// ---------------------------------------------------------------- zero
__global__ __launch_bounds__(256) void k_zero(float4* __restrict__ p, int n4) {
  int i = blockIdx.x * 256 + threadIdx.x;
  if (i < n4) p[i] = make_float4(0.f, 0.f, 0.f, 0.f);
}

// ---------------------------------------------------------------- fragment-pack all weights
// Fragment f=(kk,i): 1KB chunk, lane reads 16B at dst[f*1024 + lane*16].
// b for lane(mrow,quad) of frag (kk,i) = W[i*16+mrow][kk*32+quad*8 .. +8].
// Segments: We 32 frags | Wo 40 | Wu 2x100 | Wp 2x2x50.  472 frags x 64 lanes.
__global__ __launch_bounds__(256) void k_pack(
    const float* __restrict__ w_enc, const float* __restrict__ w_out,
    const float* __restrict__ wu, const float* __restrict__ wm,
    _Float16* __restrict__ WeP, _Float16* __restrict__ WoP,
    _Float16* __restrict__ WuP, _Float16* __restrict__ WpP) {
  int gid = blockIdx.x * 256 + threadIdx.x;  // grid exact: 118*256 = 30208 = 472*64
  int fid = gid >> 6, lane = gid & 63;
  int mrow = lane & 15, quad = lane >> 4;
  const float* src; _Float16* dst; int stride, NI, f, g;
  if (fid < 32) {
    f = fid; g = f; src = w_enc; dst = WeP; stride = 128; NI = 8;
  } else if (fid < 72) {
    f = fid - 32; g = f; src = w_out; dst = WoP; stride = 160; NI = 8;
  } else if (fid < 272) {
    f = fid - 72; g = f % 100; src = wu + (f / 100) * 51200; dst = WuP; stride = 320; NI = 10;
  } else {
    f = fid - 272; g = f % 50;
    int l = f / 100, h = (f % 100) / 50;
    src = wm + l * 51200 + h * 160; dst = WpP; stride = 320; NI = 10;
  }
  int kk = g / NI, i = g - kk * NI;
  const float* sp = src + (size_t)(i * 16 + mrow) * stride + kk * 32 + quad * 8;
  float4 f0 = *(const float4*)sp;
  float4 f1 = *(const float4*)(sp + 4);
  half8 v = {(_Float16)f0.x, (_Float16)f0.y, (_Float16)f0.z, (_Float16)f0.w,
             (_Float16)f1.x, (_Float16)f1.y, (_Float16)f1.z, (_Float16)f1.w};
  *(half8*)&dst[(size_t)(f * 64 + lane) * 8] = v;
}

// ---------------------------------------------------------------- CSR build
__global__ __launch_bounds__(256) void k_count_i(const int* __restrict__ ei,
                                                 int* __restrict__ cnti) {
  int e = blockIdx.x * 256 + threadIdx.x;  // grid exact: 3125*256 = 800000
  atomicAdd(&cnti[ei[NE + e]], 1);
}

__global__ __launch_bounds__(256) void k_scan1(const int* __restrict__ cnti,
                                               int* __restrict__ off,
                                               int* __restrict__ bsum) {
  __shared__ int sh[256];
  const int t = threadIdx.x;
  const int i = blockIdx.x * 256 + t;  // grid 391 covers 100096
  int v = (i < NN) ? cnti[i] : 0;
  sh[t] = v;
  __syncthreads();
  for (int d = 1; d < 256; d <<= 1) {
    int add = (t >= d) ? sh[t - d] : 0;
    __syncthreads();
    sh[t] += add;
    __syncthreads();
  }
  if (i < NN) off[i] = sh[t] - v;
  if (t == 255) bsum[blockIdx.x] = sh[255];
}

__global__ __launch_bounds__(512) void k_scan2(const int* __restrict__ bsum,
                                               int* __restrict__ bsum2) {
  __shared__ int sh[512];
  const int t = threadIdx.x;
  int v = (t < 391) ? bsum[t] : 0;
  sh[t] = v;
  __syncthreads();
  for (int d = 1; d < 512; d <<= 1) {
    int add = (t >= d) ? sh[t - d] : 0;
    __syncthreads();
    sh[t] += add;
    __syncthreads();
  }
  if (t < 391) bsum2[t] = sh[t] - v;
}

__global__ __launch_bounds__(256) void k_scan3(int* __restrict__ off,
                                               const int* __restrict__ bsum2,
                                               int* __restrict__ cursor) {
  const int i = blockIdx.x * 256 + threadIdx.x;
  if (i < NN) {
    int o = off[i] + bsum2[blockIdx.x];
    off[i] = o;
    cursor[i] = o;
  }
  if (i == 0) off[NN] = NE;
}

__global__ __launch_bounds__(256) void k_scatter(const int* __restrict__ ei,
                                                 const float* __restrict__ ew,
                                                 int* __restrict__ cursor,
                                                 int2* __restrict__ selist) {
  int e = blockIdx.x * 256 + threadIdx.x;  // grid exact 3125
  int dst = ei[NE + e];
  int pos = atomicAdd(&cursor[dst], 1);
  selist[pos] = make_int2(ei[e], __float_as_int(ew[e]));
}

// ---------------------------------------------------------------- helpers
__device__ __forceinline__ half8 cvt8(const float* p) {
  float4 f0 = *(const float4*)p;
  float4 f1 = *(const float4*)(p + 4);
  half8 a = {(_Float16)f0.x, (_Float16)f0.y, (_Float16)f0.z, (_Float16)f0.w,
             (_Float16)f1.x, (_Float16)f1.y, (_Float16)f1.z, (_Float16)f1.w};
  return a;
}

// group loads: fragments are linear (frag = g*W + ii for group width W)
__device__ __forceinline__ void ldg5(half8 d[5], const _Float16* Wf, int g) {
#pragma unroll
  for (int ii = 0; ii < 5; ++ii) d[ii] = LDB(Wf, g * 5 + ii);
}
__device__ __forceinline__ void ldg4(half8 d[4], const _Float16* Wf, int g) {
#pragma unroll
  for (int ii = 0; ii < 4; ++ii) d[ii] = LDB(Wf, g * 4 + ii);
}

// wave-local vectorized h16 writer: 16 rows x 20 pieces = 320 chunks over 64 lanes
__device__ __forceinline__ void write_h16_wave(_Float16* __restrict__ h16,
                                               const _Float16* tile, int n0,
                                               int lane) {
#pragma unroll
  for (int u = 0; u < 5; ++u) {
    int c = lane + u * 64;
    int row = c / 20, col = (c - row * 20) * 8;
    *(half8*)&h16[(size_t)(n0 + row) * 160 + col] = *(const half8*)&tile[row * 168 + col];
  }
}

// ---------------------------------------------------------------- shared phase 2: P = tile @ Wp^T
// 1 wave, 16 rows; double-buffered 5-frag groups with cross-half prefetch.
// Precondition: bA holds half0 group0.
__device__ __forceinline__ void phase2_proj(
    const _Float16* __restrict__ WpP, const float* __restrict__ bm,
    _Float16* __restrict__ P, const _Float16* tile, half8 bA[5], half8 bB[5],
    int lane, int mrow, int quad, int n0) {
#pragma unroll
  for (int half_ = 0; half_ < 2; ++half_) {
    const _Float16* Wf = WpP + half_ * 25600 + lane * 8;
    const _Float16* Wfn = WpP + 25600 + lane * 8;
    floatx4 acc2[10];
#pragma unroll
    for (int i = 0; i < 10; ++i) acc2[i] = (floatx4)0.f;
    half8 a_cur = *(const half8*)&tile[mrow * 168 + quad * 8];
#pragma unroll
    for (int g = 0; g < 10; ++g) {
      half8* bc = (g & 1) ? bB : bA;
      half8* bn = (g & 1) ? bA : bB;
      if (g + 1 < 10) ldg5(bn, Wf, g + 1);
      else if (half_ == 0) ldg5(bn, Wfn, 0);  // prefetch next half's group0
      half8 a_use = a_cur;
      if ((g & 1) && g < 9) {
        int kk1 = (g + 1) >> 1;
        a_cur = *(const half8*)&tile[mrow * 168 + kk1 * 32 + quad * 8];
      }
      const int ib = (g & 1) * 5;
#pragma unroll
      for (int ii = 0; ii < 5; ++ii)
        acc2[ib + ii] = __builtin_amdgcn_mfma_f32_16x16x32_f16(a_use, bc[ii], acc2[ib + ii], 0, 0, 0);
    }
#pragma unroll
    for (int r = 0; r < 4; ++r) {
      const int row = quad * 4 + r;
      _Float16* prow = &P[(size_t)(n0 + row) * 320 + half_ * 160];
#pragma unroll
      for (int i = 0; i < 10; ++i) {
        int jj = i * 16 + mrow;
        prow[jj] = (_Float16)(acc2[i][r] + (half_ ? bm[jj] : 0.f));
      }
    }
  }
}

// ---------------------------------------------------------------- fused encoder + proj (64 thr, 16 nodes)
__global__ __launch_bounds__(64, 4) void k_encode_proj(
    const float* __restrict__ x, const float* __restrict__ tsp,
    const _Float16* __restrict__ WeP,
    const float* __restrict__ b_enc, const float* __restrict__ g_enc,
    const float* __restrict__ be_enc,
    const float* __restrict__ w_time, const float* __restrict__ b_time,
    const float* __restrict__ g_time, const float* __restrict__ be_time,
    const _Float16* __restrict__ WpP, const float* __restrict__ bm,
    _Float16* __restrict__ h16, _Float16* __restrict__ P) {
  __shared__ _Float16 tile[16 * 168];
  const int lane = threadIdx.x;
  const int mrow = lane & 15, quad = lane >> 4;
  const int n0 = blockIdx.x * 16;  // grid 6250 exact
  const float* xrow = x + (size_t)(n0 + mrow) * 128;
  const _Float16* Wf = WeP + lane * 8;
  half8 cA[4], cB[4];
  ldg4(cA, Wf, 0);
  // time-LN closed-form constants (hides group-0 latency)
  float mw = 0.f, mb = 0.f;
  for (int d = 0; d < 32; ++d) { mw += w_time[d]; mb += b_time[d]; }
  mw *= (1.f / 32.f); mb *= (1.f / 32.f);
  float A = 0.f, B = 0.f, C = 0.f;
  for (int d = 0; d < 32; ++d) {
    float a = w_time[d] - mw, c = b_time[d] - mb;
    A = fmaf(a, a, A); B = fmaf(a, c, B); C = fmaf(c, c, C);
  }
  A *= (1.f / 32.f); B *= (1.f / 32.f); C *= (1.f / 32.f);
  // phase 1: h = x @ We^T — 8 groups of 4, double-buffered
  floatx4 acc[8];
#pragma unroll
  for (int i = 0; i < 8; ++i) acc[i] = (floatx4)0.f;
  half8 a_cur = cvt8(&xrow[quad * 8]);
#pragma unroll
  for (int g = 0; g < 8; ++g) {
    half8* bc = (g & 1) ? cB : cA;
    half8* bn = (g & 1) ? cA : cB;
    if (g + 1 < 8) ldg4(bn, Wf, g + 1);
    half8 a_use = a_cur;
    if ((g & 1) && g < 7) {
      int kk1 = (g + 1) >> 1;
      a_cur = cvt8(&xrow[kk1 * 32 + quad * 8]);
    }
    const int ib = (g & 1) * 4;
#pragma unroll
    for (int ii = 0; ii < 4; ++ii)
      acc[ib + ii] = __builtin_amdgcn_mfma_f32_16x16x32_f16(a_use, bc[ii], acc[ib + ii], 0, 0, 0);
  }
  // prefetch phase-2 half0 group0 (hides under epilogue VALU)
  half8 bA[5], bB[5];
  ldg5(bA, WpP + lane * 8, 0);
  // epilogue: LN(128) + relu -> tile
#pragma unroll
  for (int r = 0; r < 4; ++r) {
    const int row = quad * 4 + r;
    float v[8], s = 0.f, ss = 0.f;
#pragma unroll
    for (int i = 0; i < 8; ++i) {
      v[i] = acc[i][r] + b_enc[i * 16 + mrow];
      s += v[i]; ss = fmaf(v[i], v[i], ss);
    }
#pragma unroll
    for (int off = 1; off < 16; off <<= 1) { s += __shfl_xor(s, off); ss += __shfl_xor(ss, off); }
    const float m = s * (1.f / 128.f);
    const float rs = rsqrtf(ss * (1.f / 128.f) - m * m + 1e-5f);
#pragma unroll
    for (int i = 0; i < 8; ++i) {
      int j = i * 16 + mrow;
      tile[row * 168 + j] =
          (_Float16)fmaxf(fmaf((v[i] - m) * rs, g_enc[j], be_enc[j]), 0.f);
    }
  }
  // time dims 128..159 (closed-form LN): 16 nodes x 32 dims = 512
#pragma unroll
  for (int rr = 0; rr < 8; ++rr) {
    int q = lane + rr * 64;
    int nn = q >> 5, d = q & 31;
    float tsv = tsp[n0 + nn];
    float mt = fmaf(mw, tsv, mb);
    float rst = rsqrtf(fmaf(fmaf(A, tsv, 2.f * B), tsv, C) + 1e-5f);
    float vv = fmaf(w_time[d], tsv, b_time[d]);
    float y = fmaxf(fmaf((vv - mt) * rst, g_time[d], be_time[d]), 0.f);
    tile[nn * 168 + 128 + d] = (_Float16)y;
  }
  // wave-local tile handoff (no barrier)
  write_h16_wave(h16, tile, n0, lane);
  phase2_proj(WpP, bm, P, tile, bA, bB, lane, mrow, quad, n0);
}

// ---------------------------------------------------------------- edge aggregate (CSR, 2-way unroll)
__global__ __launch_bounds__(256) void k_edge3(
    const _Float16* __restrict__ P, const int* __restrict__ off,
    const int2* __restrict__ selist,
    const float* __restrict__ gm, const float* __restrict__ bem,
    _Float16* __restrict__ msum16) {
  const int t = threadIdx.x;
  const int jg = t & 31, g = t >> 5;
  const int n = blockIdx.x * 8 + g;  // grid exact: 12500*8 = 100000
  float gmv[5], bev[5], pdv[5];
#pragma unroll
  for (int i = 0; i < 4; ++i) { gmv[i] = gm[4 * jg + i]; bev[i] = bem[4 * jg + i]; }
  gmv[4] = gm[128 + jg]; bev[4] = bem[128 + jg];
  const _Float16* pd = P + (size_t)n * 320 + 160;
  half4 pdh = *(const half4*)&pd[4 * jg];
  pdv[0] = (float)pdh.x; pdv[1] = (float)pdh.y; pdv[2] = (float)pdh.z; pdv[3] = (float)pdh.w;
  pdv[4] = (float)pd[128 + jg];
  float acc[5] = {0.f, 0.f, 0.f, 0.f, 0.f};
  const int e0 = off[n], e1 = off[n + 1];
  int k = e0;
  for (; k + 1 < e1; k += 2) {
    int2 seA = selist[k], seB = selist[k + 1];
    const _Float16* psA = P + (size_t)seA.x * 320;
    const _Float16* psB = P + (size_t)seB.x * 320;
    const float weA = __int_as_float(seA.y), weB = __int_as_float(seB.y);
    half4 a4 = *(const half4*)&psA[4 * jg];
    half4 b4 = *(const half4*)&psB[4 * jg];
    float a5 = (float)psA[128 + jg], b5 = (float)psB[128 + jg];
    float vA[5], vB[5];
    vA[0] = (float)a4.x + pdv[0]; vA[1] = (float)a4.y + pdv[1];
    vA[2] = (float)a4.z + pdv[2]; vA[3] = (float)a4.w + pdv[3]; vA[4] = a5 + pdv[4];
    vB[0] = (float)b4.x + pdv[0]; vB[1] = (float)b4.y + pdv[1];
    vB[2] = (float)b4.z + pdv[2]; vB[3] = (float)b4.w + pdv[3]; vB[4] = b5 + pdv[4];
    float sA = 0.f, ssA = 0.f, sB = 0.f, ssB = 0.f;
#pragma unroll
    for (int i = 0; i < 5; ++i) {
      sA += vA[i]; ssA = fmaf(vA[i], vA[i], ssA);
      sB += vB[i]; ssB = fmaf(vB[i], vB[i], ssB);
    }
#pragma unroll
    for (int o = 1; o < 32; o <<= 1) {
      sA += __shfl_xor(sA, o); ssA += __shfl_xor(ssA, o);
      sB += __shfl_xor(sB, o); ssB += __shfl_xor(ssB, o);
    }
    const float mA = sA * (1.f / 160.f), mB = sB * (1.f / 160.f);
    const float rsA = rsqrtf(ssA * (1.f / 160.f) - mA * mA + 1e-5f);
    const float rsB = rsqrtf(ssB * (1.f / 160.f) - mB * mB + 1e-5f);
#pragma unroll
    for (int i = 0; i < 5; ++i) {
      acc[i] = fmaf(fmaxf(fmaf((vA[i] - mA) * rsA, gmv[i], bev[i]), 0.f), weA, acc[i]);
      acc[i] = fmaf(fmaxf(fmaf((vB[i] - mB) * rsB, gmv[i], bev[i]), 0.f), weB, acc[i]);
    }
  }
  if (k < e1) {
    int2 se = selist[k];
    const _Float16* ps = P + (size_t)se.x * 320;
    const float we = __int_as_float(se.y);
    half4 s4 = *(const half4*)&ps[4 * jg];
    float v[5], s = 0.f, ss = 0.f;
    v[0] = (float)s4.x + pdv[0]; v[1] = (float)s4.y + pdv[1];
    v[2] = (float)s4.z + pdv[2]; v[3] = (float)s4.w + pdv[3];
    v[4] = (float)ps[128 + jg] + pdv[4];
#pragma unroll
    for (int i = 0; i < 5; ++i) { s += v[i]; ss = fmaf(v[i], v[i], ss); }
#pragma unroll
    for (int o = 1; o < 32; o <<= 1) { s += __shfl_xor(s, o); ss += __shfl_xor(ss, o); }
    const float m = s * (1.f / 160.f);
    const float rs = rsqrtf(ss * (1.f / 160.f) - m * m + 1e-5f);
#pragma unroll
    for (int i = 0; i < 5; ++i)
      acc[i] = fmaf(fmaxf(fmaf((v[i] - m) * rs, gmv[i], bev[i]), 0.f), we, acc[i]);
  }
  const float c = (float)(e1 - e0);
  const float ic = (c > 0.f) ? 1.f / (c + 1e-8f) : 0.f;
  _Float16* orow = msum16 + (size_t)n * 160;
  half4 o4 = {(_Float16)(acc[0] * ic), (_Float16)(acc[1] * ic),
              (_Float16)(acc[2] * ic), (_Float16)(acc[3] * ic)};
  *(half4*)&orow[4 * jg] = o4;
  orow[128 + jg] = (_Float16)(acc[4] * ic);
}

// ---------------------------------------------------------------- shared update phase 1 -> tile (1 wave, 16 rows)
// Double-buffered 5-frag groups; on exit bA holds phase-2 half0 group0.
__device__ __forceinline__ void update_phase1(
    const _Float16* __restrict__ h16, const _Float16* __restrict__ msum16,
    const _Float16* __restrict__ WuP, const float* __restrict__ bu,
    const float* __restrict__ gu, const float* __restrict__ beu,
    const float* __restrict__ wg, const float* __restrict__ bg,
    const _Float16* __restrict__ WpPf,  // phase-2 prefetch base (+lane*8 applied by caller)
    _Float16* tile, half8 bA[5], half8 bB[5],
    int lane, int mrow, int quad, int n0) {
  const _Float16* h0 = h16 + (size_t)(n0 + mrow) * 160;
  const _Float16* ms0 = msum16 + (size_t)(n0 + mrow) * 160;
  const _Float16* Wf = WuP + lane * 8;
  ldg5(bA, Wf, 0);
  // gate dot (transient h loads; hides group-0 latency)
  float gp = 0.f;
#pragma unroll
  for (int kt = 0; kt < 5; ++kt) {
    half8 ha = *(const half8*)&h0[kt * 32 + quad * 8];
    float4 g0 = *(const float4*)&wg[kt * 32 + quad * 8];
    float4 g1 = *(const float4*)&wg[kt * 32 + quad * 8 + 4];
    gp = fmaf((float)ha[0], g0.x, gp); gp = fmaf((float)ha[1], g0.y, gp);
    gp = fmaf((float)ha[2], g0.z, gp); gp = fmaf((float)ha[3], g0.w, gp);
    gp = fmaf((float)ha[4], g1.x, gp); gp = fmaf((float)ha[5], g1.y, gp);
    gp = fmaf((float)ha[6], g1.z, gp); gp = fmaf((float)ha[7], g1.w, gp);
  }
  gp += __shfl_xor(gp, 16); gp += __shfl_xor(gp, 32);
  const float twv = 1.f / (1.f + expf(-(gp + bg[0])));
  // K=320: 20 groups of 5, double-buffered, zero barriers
  floatx4 acc[10];
#pragma unroll
  for (int i = 0; i < 10; ++i) acc[i] = (floatx4)0.f;
  half8 a_cur = *(const half8*)&h0[quad * 8];
#pragma unroll
  for (int g = 0; g < 20; ++g) {
    half8* bc = (g & 1) ? bB : bA;
    half8* bn = (g & 1) ? bA : bB;
    if (g + 1 < 20) ldg5(bn, Wf, g + 1);
    half8 a_use = a_cur;
    if ((g & 1) && g < 19) {
      int kk1 = (g + 1) >> 1;
      const _Float16* ap = (kk1 < 5) ? h0 + kk1 * 32 : ms0 + (kk1 - 5) * 32;
      a_cur = *(const half8*)&ap[quad * 8];
    }
    const int ib = (g & 1) * 5;
#pragma unroll
    for (int ii = 0; ii < 5; ++ii)
      acc[ib + ii] = __builtin_amdgcn_mfma_f32_16x16x32_f16(a_use, bc[ii], acc[ib + ii], 0, 0, 0);
  }
  // prefetch phase-2 group0 into bA (last bA read was g=18; hides under epilogue)
  ldg5(bA, WpPf, 0);
  // epilogue: LN + relu + gate blend -> tile
#pragma unroll
  for (int r = 0; r < 4; ++r) {
    const int row = quad * 4 + r;
    float v[10], s = 0.f, ss = 0.f;
#pragma unroll
    for (int i = 0; i < 10; ++i) {
      v[i] = acc[i][r] + bu[i * 16 + mrow];
      s += v[i]; ss = fmaf(v[i], v[i], ss);
    }
#pragma unroll
    for (int off = 1; off < 16; off <<= 1) { s += __shfl_xor(s, off); ss += __shfl_xor(ss, off); }
    const float m = s * (1.f / 160.f);
    const float rs = rsqrtf(ss * (1.f / 160.f) - m * m + 1e-5f);
    const float g = __shfl(twv, row);
    const _Float16* hr = h16 + (size_t)(n0 + row) * 160;
#pragma unroll
    for (int i = 0; i < 10; ++i) {
      int j = i * 16 + mrow;
      float hnew = fmaxf(fmaf((v[i] - m) * rs, gu[j], beu[j]), 0.f);
      float hold = (float)hr[j];
      tile[row * 168 + j] = (_Float16)fmaf(g, hnew - hold, hold);
    }
  }
}

// ---------------------------------------------------------------- fused update + proj (64 thr, 16 nodes)
__global__ __launch_bounds__(64, 4) void k_update_proj(
    _Float16* __restrict__ h16, const _Float16* __restrict__ msum16,
    const _Float16* __restrict__ WuP, const float* __restrict__ bu,
    const float* __restrict__ gu, const float* __restrict__ beu,
    const float* __restrict__ wg, const float* __restrict__ bg,
    const _Float16* __restrict__ WpP, const float* __restrict__ bm,
    _Float16* __restrict__ P) {
  __shared__ _Float16 tile[16 * 168];
  const int lane = threadIdx.x;
  const int mrow = lane & 15, quad = lane >> 4;
  const int n0 = blockIdx.x * 16;  // grid 6250 exact
  half8 bA[5], bB[5];
  update_phase1(h16, msum16, WuP, bu, gu, beu, wg, bg,
                WpP + lane * 8, tile, bA, bB, lane, mrow, quad, n0);
  write_h16_wave(h16, tile, n0, lane);
  phase2_proj(WpP, bm, P, tile, bA, bB, lane, mrow, quad, n0);
}

// ---------------------------------------------------------------- fused update + output proj + L2 norm
__global__ __launch_bounds__(64, 4) void k_update_out(
    const _Float16* __restrict__ h16, const _Float16* __restrict__ msum16,
    const _Float16* __restrict__ WuP, const float* __restrict__ bu,
    const float* __restrict__ gu, const float* __restrict__ beu,
    const float* __restrict__ wg, const float* __restrict__ bg,
    const _Float16* __restrict__ WoP, const float* __restrict__ b_out,
    float* __restrict__ out) {
  __shared__ _Float16 tile[16 * 168];
  const int lane = threadIdx.x;
  const int mrow = lane & 15, quad = lane >> 4;
  const int n0 = blockIdx.x * 16;  // grid 6250 exact
  half8 bA[5], bB[5];
  // phase-2 here uses Wo groups of 4; reuse bA[0..3] slot via dedicated buffers below.
  update_phase1(h16, msum16, WuP, bu, gu, beu, wg, bg,
                WoP + lane * 8, tile, bA, bB, lane, mrow, quad, n0);
  // NOTE: update_phase1 prefetched ldg5(bA, WoP..., 0) = Wo frags 0..4; phase-2 groups
  // are width-4, so do NOT use the prefetch directly — copy overlap: frags 0..3 = group 0.
  const _Float16* Wf2 = WoP + lane * 8;
  half8 cA[4], cB[4];
#pragma unroll
  for (int ii = 0; ii < 4; ++ii) cA[ii] = bA[ii];  // group 0 already in regs
  // phase 2: out = L2norm(tile @ Wo^T + b_out); 10 groups of 4, double-buffered
  floatx4 acc2[8];
#pragma unroll
  for (int i = 0; i < 8; ++i) acc2[i] = (floatx4)0.f;
  half8 a_cur = *(const half8*)&tile[mrow * 168 + quad * 8];
#pragma unroll
  for (int g = 0; g < 10; ++g) {
    half8* bc = (g & 1) ? cB : cA;
    half8* bn = (g & 1) ? cA : cB;
    if (g + 1 < 10) ldg4(bn, Wf2, g + 1);
    half8 a_use = a_cur;
    if ((g & 1) && g < 9) {
      int kk1 = (g + 1) >> 1;
      a_cur = *(const half8*)&tile[mrow * 168 + kk1 * 32 + quad * 8];
    }
    const int ib = (g & 1) * 4;
#pragma unroll
    for (int ii = 0; ii < 4; ++ii)
      acc2[ib + ii] = __builtin_amdgcn_mfma_f32_16x16x32_f16(a_use, bc[ii], acc2[ib + ii], 0, 0, 0);
  }
#pragma unroll
  for (int r = 0; r < 4; ++r) {
    const int row = quad * 4 + r;
    float v[8], ss = 0.f;
#pragma unroll
    for (int i = 0; i < 8; ++i) {
      v[i] = acc2[i][r] + b_out[i * 16 + mrow];
      ss = fmaf(v[i], v[i], ss);
    }
#pragma unroll
    for (int off = 1; off < 16; off <<= 1) ss += __shfl_xor(ss, off);
    const float inv = 1.f / fmaxf(sqrtf(ss), 1e-12f);
#pragma unroll
    for (int i = 0; i < 8; ++i)
      out[(size_t)(n0 + row) * 128 + i * 16 + mrow] = v[i] * inv;
  }
}

// ---------------------------------------------------------------- launch
extern "C" void kernel_launch(void* const* d_in, const int* in_sizes, int n_in,
                              void* d_out, int out_size, void* d_ws, size_t ws_size,
                              hipStream_t stream) {
  (void)in_sizes; (void)n_in; (void)out_size; (void)ws_size;
  const float* x       = (const float*)d_in[0];
  const int*   ei      = (const int*)  d_in[1];
  const float* ew      = (const float*)d_in[2];
  const float* tsp     = (const float*)d_in[3];
  const float* w_enc   = (const float*)d_in[4];
  const float* b_enc   = (const float*)d_in[5];
  const float* g_enc   = (const float*)d_in[6];
  const float* be_enc  = (const float*)d_in[7];
  const float* w_time  = (const float*)d_in[8];
  const float* b_time  = (const float*)d_in[9];
  const float* g_time  = (const float*)d_in[10];
  const float* be_time = (const float*)d_in[11];
  const float* wm      = (const float*)d_in[12];
  const float* bm      = (const float*)d_in[13];
  const float* gm      = (const float*)d_in[14];
  const float* bem     = (const float*)d_in[15];
  const float* wu      = (const float*)d_in[16];
  const float* bu      = (const float*)d_in[17];
  const float* gu      = (const float*)d_in[18];
  const float* beu     = (const float*)d_in[19];
  const float* wg      = (const float*)d_in[20];
  const float* bg      = (const float*)d_in[21];
  const float* w_out   = (const float*)d_in[22];
  const float* b_out   = (const float*)d_in[23];
  float* out = (float*)d_out;

  // ws layout (bytes): h16 f16[NN*160] @0 (32M) | msum16 f16[NN*160] @32,000,000 (32M)
  //   P f16[NN*320] @64,000,000 (64M) | WuP @128,000,000 (204,800) | WoP @128,204,800 (40,960)
  char* ws = (char*)d_ws;
  _Float16* h16    = (_Float16*)ws;
  _Float16* msum16 = (_Float16*)(ws + 32000000);
  _Float16* P      = (_Float16*)(ws + 64000000);
  _Float16* WuP16  = (_Float16*)(ws + 128000000);
  _Float16* WoP16  = (_Float16*)(ws + 128204800);
  // d_out doubles as scratch; k_update_out reads only ws-resident scratch.
  char* ob = (char*)d_out;
  _Float16* WpP16 = (_Float16*)ob;            // 204,800
  _Float16* WeP16 = (_Float16*)(ob + 204800); // 32,768
  int* off    = (int*)(ob + 237568);          // 400,016
  int* cnti   = (int*)(ob + 637584);          // 400,000
  int* cursor = (int*)(ob + 1037584);         // 400,000
  int* bsum   = (int*)(ob + 1437584);         // 1,568
  int* bsum2  = (int*)(ob + 1439152);         // 1,568
  int2* selist = (int2*)(ob + 1440720);       // 6,400,000 -> 7,840,720 < 51,200,000

  // weight prep + CSR build (edges static across layers: build once)
  k_zero<<<dim3(98), dim3(256), 0, stream>>>((float4*)cnti, 25000);
  k_pack<<<dim3(118), dim3(256), 0, stream>>>(w_enc, w_out, wu, wm,
                                              WeP16, WoP16, WuP16, WpP16);
  k_count_i<<<dim3(3125), dim3(256), 0, stream>>>(ei, cnti);
  k_scan1<<<dim3(391), dim3(256), 0, stream>>>(cnti, off, bsum);
  k_scan2<<<dim3(1), dim3(512), 0, stream>>>(bsum, bsum2);
  k_scan3<<<dim3(391), dim3(256), 0, stream>>>(off, bsum2, cursor);
  k_scatter<<<dim3(3125), dim3(256), 0, stream>>>(ei, ew, cursor, selist);

  k_encode_proj<<<dim3(6250), dim3(64), 0, stream>>>(
      x, tsp, WeP16, b_enc, g_enc, be_enc, w_time, b_time, g_time, be_time,
      WpP16, bm, h16, P);
  k_edge3<<<dim3(12500), dim3(256), 0, stream>>>(P, off, selist, gm, bem, msum16);
  k_update_proj<<<dim3(6250), dim3(64), 0, stream>>>(
      h16, msum16, WuP16, bu, gu, beu, wg, bg,
      WpP16 + 51200, bm + 160, P);
  k_edge3<<<dim3(12500), dim3(256), 0, stream>>>(P, off, selist, gm + 160, bem + 160, msum16);
  k_update_out<<<dim3(6250), dim3(64), 0, stream>>>(
      h16, msum16, WuP16 + 51200, bu + 160, gu + 160, beu + 160, wg + 160, bg + 1,
      WoP16, b_out, out);
}